// Round 1
// baseline (2282.960 us; speedup 1.0000x reference)
//
#include <hip/hip_runtime.h>
#include <hip/hip_bf16.h>
#include <cstdint>

// Problem constants: H=512, B=64, S=512, D=512, N_AUX=2
#define B_ 64
#define S_ 512
#define D_ 512
#define H_ 512
#define M_ (B_*S_)   // 32768
#define G3_ (3*H_)   // 1536
#define G2_ (2*H_)   // 1024

using floatx4  = __attribute__((ext_vector_type(4))) float;
using shortx8  = __attribute__((ext_vector_type(8))) short;
using ushortx4 = __attribute__((ext_vector_type(4))) unsigned short;
using uintx4   = __attribute__((ext_vector_type(4))) unsigned int;

__device__ __forceinline__ unsigned short f32_to_bf16(float f) {
    union { float f; uint32_t u; } v; v.f = f;
    uint32_t u = v.u;
    return (unsigned short)((u + 0x7FFFu + ((u >> 16) & 1u)) >> 16);
}
__device__ __forceinline__ float bf16_to_f32(unsigned short s) {
    union { uint32_t u; float f; } v; v.u = ((uint32_t)s) << 16;
    return v.f;
}

// LLC-coherent (device coherent point) access helpers. sc0 sc1 bypass the
// per-CU L1 and the per-XCD L2, completing at the MALL/LLC — correct for
// cross-XCD producer/consumer without any cache-wide wbinv ops.
__device__ __forceinline__ void store_llc_b64(void* p, unsigned long long v) {
    asm volatile("global_store_dwordx2 %0, %1, off sc0 sc1"
                 :: "v"(p), "v"(v) : "memory");
}
__device__ __forceinline__ uintx4 load_llc_b128(const void* p) {
    uintx4 r;
    asm volatile("global_load_dwordx4 %0, %1, off sc0 sc1"
                 : "=v"(r) : "v"(p) : "memory");
    return r;
}

// ---------------------------------------------------------------------------
// fp32 -> bf16 bulk convert (n % 4 == 0)
// ---------------------------------------------------------------------------
__global__ __launch_bounds__(256) void cvt_bf16(
    const float* __restrict__ in, unsigned short* __restrict__ outp, int n)
{
    int idx = (blockIdx.x * 256 + threadIdx.x) * 4;
    if (idx < n) {
        floatx4 v = *(const floatx4*)(in + idx);
        ushortx4 o;
        #pragma unroll
        for (int u = 0; u < 4; ++u) o[u] = f32_to_bf16(v[u]);
        *(ushortx4*)(outp + idx) = o;
    }
}

// ---------------------------------------------------------------------------
// 128x128-tile bf16 MFMA GEMM (m93-style, register-staged LDS, padded rows).
// out[(s*B+b)][n] = scale * ( sum_a A_a[m,:].W_a[n,:] + sum_a bias_a[n] ),
// m = b*S + s. A bf16 [streams][M][512], W bf16 [streams][N][512].
// ---------------------------------------------------------------------------
#define LDK 40   // 32 + 8 shorts pad: row stride 80B = 20 banks -> conflict-free
__global__ __launch_bounds__(256) void proj_gemm128(
    const unsigned short* __restrict__ A, const unsigned short* __restrict__ Wb,
    const float* __restrict__ bias, unsigned short* __restrict__ out,
    int N, int nstreams, float scale, size_t a_stride, size_t w_stride)
{
    __shared__ unsigned short ldsA[128 * LDK];
    __shared__ unsigned short ldsB[128 * LDK];
    const int tid  = threadIdx.x;
    const int lane = tid & 63;
    const int wv   = tid >> 6;
    const int m0   = blockIdx.x * 128;
    const int n0   = blockIdx.y * 128;
    const int wm   = (wv & 1) * 64;
    const int wn   = (wv >> 1) * 64;
    const int srow  = tid >> 2;   // 0..63
    const int spart = tid & 3;    // 0..3

    floatx4 acc[4][4] = {};

    for (int a = 0; a < nstreams; ++a) {
        const unsigned short* Aa = A  + (size_t)a * a_stride;
        const unsigned short* Wa = Wb + (size_t)a * w_stride;
        for (int kt = 0; kt < 16; ++kt) {
            const int k0 = kt * 32;
            #pragma unroll
            for (int h = 0; h < 2; ++h) {
                int row = srow + h * 64;
                *(shortx8*)(ldsA + row * LDK + spart * 8) =
                    *(const shortx8*)(Aa + (size_t)(m0 + row) * 512 + k0 + spart * 8);
                *(shortx8*)(ldsB + row * LDK + spart * 8) =
                    *(const shortx8*)(Wa + (size_t)(n0 + row) * 512 + k0 + spart * 8);
            }
            __syncthreads();
            shortx8 af[4], bf[4];
            #pragma unroll
            for (int i = 0; i < 4; ++i)
                af[i] = *(const shortx8*)(ldsA + (wm + i * 16 + (lane & 15)) * LDK + (lane >> 4) * 8);
            #pragma unroll
            for (int j = 0; j < 4; ++j)
                bf[j] = *(const shortx8*)(ldsB + (wn + j * 16 + (lane & 15)) * LDK + (lane >> 4) * 8);
            #pragma unroll
            for (int i = 0; i < 4; ++i)
                #pragma unroll
                for (int j = 0; j < 4; ++j)
                    acc[i][j] = __builtin_amdgcn_mfma_f32_16x16x32_bf16(af[i], bf[j], acc[i][j], 0, 0, 0);
            __syncthreads();
        }
    }

    #pragma unroll
    for (int j = 0; j < 4; ++j) {
        int n = n0 + wn + j * 16 + (lane & 15);
        float bsum = 0.f;
        for (int a = 0; a < nstreams; ++a) bsum += bias[a * N + n];
        #pragma unroll
        for (int i = 0; i < 4; ++i) {
            #pragma unroll
            for (int r = 0; r < 4; ++r) {
                int m = m0 + wm + i * 16 + (lane >> 4) * 4 + r;
                int b = m >> 9, s = m & (S_ - 1);
                out[((size_t)s * B_ + b) * N + n] = f32_to_bf16(scale * (acc[i][j][r] + bsum));
            }
        }
    }
}

// ---------------------------------------------------------------------------
// Transpose bf16 [S][B][G] -> [S][G][B]
// ---------------------------------------------------------------------------
__global__ __launch_bounds__(256) void transpose_to_sgb(
    const unsigned short* __restrict__ in, unsigned short* __restrict__ out, int G)
{
    __shared__ unsigned short tile[64][66];
    const int s  = blockIdx.x;
    const int g0 = blockIdx.y * 64;
    const int c  = threadIdx.x & 63;
    const int r0 = threadIdx.x >> 6;
    #pragma unroll
    for (int i = 0; i < 16; ++i) {
        int b = r0 * 16 + i;
        tile[b][c] = in[((size_t)s * B_ + b) * G + g0 + c];      // coalesced in g
    }
    __syncthreads();
    #pragma unroll
    for (int i = 0; i < 16; ++i) {
        int gg = r0 * 16 + i;
        out[((size_t)s * G + g0 + gg) * B_ + c] = tile[c][gg];   // coalesced in b
    }
}

// ---------------------------------------------------------------------------
// Scan init: hA[0] from hx in A-fragment layout; zero flags.
// hA short index for (b,j): ((j>>5)*4+(b>>4))*512 + ((j>>3)&3)*128 + (b&15)*8 + (j&7)
// ---------------------------------------------------------------------------
__global__ __launch_bounds__(256) void scan_init(
    const float* __restrict__ hx, unsigned short* __restrict__ hA,
    unsigned* __restrict__ flags)
{
    int idx = blockIdx.x * 256 + threadIdx.x;   // 0..32767 (grid 128!)
    int b = idx >> 9, j = idx & (H_ - 1);
    hA[(size_t)((j >> 5) * 4 + (b >> 4)) * 512 + ((j >> 3) & 3) * 128 + (b & 15) * 8 + (j & 7)]
        = f32_to_bf16(hx[idx]);
    if (idx < 128) flags[idx] = 0;
}

// ---------------------------------------------------------------------------
// Persistent scan. 128 blocks x 64 threads (1 wave). Block = (bg = blk>>5,
// jsl = blk&31): owns j = jsl*16..+16, b-group bg (16 b). W frags in LDS.
//
// Fence-free handoff: hA + flags accessed ONLY via sc0/sc1 (LLC-coherent)
// ops. Producer: hA store -> s_waitcnt vmcnt(0) -> relaxed agent flag store.
// Consumer: relaxed agent flag poll -> batched sc0/sc1 hA loads. No
// buffer_wbl2/buffer_inv (agent acq/rel fences) anywhere in the loop — those
// were full per-XCD-L2 maintenance ops paid twice per block per step.
// ---------------------------------------------------------------------------
__global__ __launch_bounds__(64) void scan_persist(
    const unsigned short* __restrict__ git,  // [S][3H][B] bf16
    const unsigned short* __restrict__ ft,   // [S][2H][B] bf16
    const float* __restrict__ Whh,           // [3H][H]
    const float* __restrict__ bhh,           // [3H]
    const float* __restrict__ hx,            // [B][H]
    unsigned short* __restrict__ hA,         // [2][32768] bf16
    unsigned* __restrict__ flags,            // [128]
    float* __restrict__ out,                 // [B][S][H]
    float* __restrict__ hfin)                // [B][H]
{
    __shared__ shortx8 ldsW[3 * 16 * 64];    // 48 KB
    __shared__ unsigned short repack[256];   // 512 B

    const int lane = threadIdx.x;
    const int jsl  = blockIdx.x & 31;
    const int bg   = blockIdx.x >> 5;
    const int j0   = jsl * 16;
    const int jn   = lane & 15;
    const int q    = lane >> 4;
    const int j    = j0 + jn;
    const int b0   = bg * 16 + q * 4;

    // one-time: W fragments -> LDS
    #pragma unroll
    for (int g = 0; g < 3; ++g) {
        const float* wrow = Whh + (size_t)(g * H_ + j0 + jn) * H_ + q * 8;
        for (int kt = 0; kt < 16; ++kt) {
            floatx4 w0 = *(const floatx4*)(wrow + kt * 32);
            floatx4 w1 = *(const floatx4*)(wrow + kt * 32 + 4);
            shortx8 wf;
            #pragma unroll
            for (int u = 0; u < 4; ++u) {
                wf[u]     = (short)f32_to_bf16(w0[u]);
                wf[u + 4] = (short)f32_to_bf16(w1[u]);
            }
            ldsW[(g * 16 + kt) * 64 + lane] = wf;
        }
    }
    const float brg = bhh[j], big = bhh[H_ + j], bng = bhh[2 * H_ + j];

    float hprev[4];
    #pragma unroll
    for (int r = 0; r < 4; ++r) hprev[r] = hx[(size_t)(b0 + r) * H_ + j];

    // gate prefetch registers (t = 0)
    ushortx4 pgr, pgi, pgn, pfr, pfi;
    {
        const unsigned short* gp = git + ((size_t)j) * B_ + b0;
        pgr = *(const ushortx4*)(gp);
        pgi = *(const ushortx4*)(gp + (size_t)H_ * B_);
        pgn = *(const ushortx4*)(gp + (size_t)2 * H_ * B_);
        const unsigned short* fp = ft + ((size_t)j) * B_ + b0;
        pfr = *(const ushortx4*)(fp);
        pfi = *(const ushortx4*)(fp + (size_t)H_ * B_);
    }

    const int slab = (jsl >> 1) * 4 + bg;
    unsigned* myflags = flags + bg * 32;

    for (int t = 0; t < S_; ++t) {
        const int buf = t & 1, nbuf = buf ^ 1;

        // --- batched hA fragment loads (pay LLC latency once) -------------
        const unsigned short* hAp = hA + (size_t)buf * 32768 + (size_t)(bg * 64 + lane) * 8;
        uintx4 af16[16];
        #pragma unroll
        for (int kt = 0; kt < 16; ++kt)
            af16[kt] = load_llc_b128(hAp + (size_t)kt * 2048);
        asm volatile("s_waitcnt vmcnt(0)" ::: "memory");
        __builtin_amdgcn_sched_barrier(0);   // keep MFMAs below the waitcnt

        floatx4 ar = {0.f,0.f,0.f,0.f}, ai = {0.f,0.f,0.f,0.f}, an = {0.f,0.f,0.f,0.f};
        #pragma unroll
        for (int kt = 0; kt < 16; ++kt) {
            shortx8 af = __builtin_bit_cast(shortx8, af16[kt]);
            ar = __builtin_amdgcn_mfma_f32_16x16x32_bf16(af, ldsW[(0 * 16 + kt) * 64 + lane], ar, 0, 0, 0);
            ai = __builtin_amdgcn_mfma_f32_16x16x32_bf16(af, ldsW[(1 * 16 + kt) * 64 + lane], ai, 0, 0, 0);
            an = __builtin_amdgcn_mfma_f32_16x16x32_bf16(af, ldsW[(2 * 16 + kt) * 64 + lane], an, 0, 0, 0);
        }

        float hy[4];
        #pragma unroll
        for (int r = 0; r < 4; ++r) {
            const float cr = bf16_to_f32(pgr[r]) + bf16_to_f32(pfr[r]);
            const float ci = bf16_to_f32(pgi[r]) + bf16_to_f32(pfi[r]);
            const float cn = bf16_to_f32(pgn[r]);
            const float rg = 1.f / (1.f + __expf(-(cr + ar[r] + brg)));
            const float ig = 1.f / (1.f + __expf(-(ci + ai[r] + big)));
            const float ng = tanhf(cn + rg * (an[r] + bng));
            hy[r] = ng + ig * (hprev[r] - ng);
            hprev[r] = hy[r];
            repack[(jn >> 3) * 128 + (q * 4 + r) * 8 + (jn & 7)] = f32_to_bf16(hy[r]);
        }
        __syncthreads();   // LDS repack visibility within the wave

        {   // publish h slab to LLC (bypass L1/L2)
            unsigned long long v = *(const unsigned long long*)(repack + lane * 4);
            store_llc_b64(hA + (size_t)nbuf * 32768 + (size_t)slab * 512
                          + (jsl & 1) * 256 + lane * 4, v);
        }

        if (t < S_ - 1) {
            // data-before-flag ordering: wait for hA store completion at LLC
            asm volatile("s_waitcnt vmcnt(0)" ::: "memory");
            if (lane == 0)
                __hip_atomic_store(&myflags[jsl], (unsigned)(t + 1),
                                   __ATOMIC_RELAXED, __HIP_MEMORY_SCOPE_AGENT);
            // off-critical-path work drains during the spin:
            #pragma unroll
            for (int r = 0; r < 4; ++r)
                out[(size_t)(b0 + r) * (S_ * H_) + (size_t)t * H_ + j] = hy[r];
            {   // prefetch gates for t+1 (plain cached loads — L2 stays warm now)
                const unsigned short* gp = git + ((size_t)(t + 1) * G3_ + j) * B_ + b0;
                pgr = *(const ushortx4*)(gp);
                pgi = *(const ushortx4*)(gp + (size_t)H_ * B_);
                pgn = *(const ushortx4*)(gp + (size_t)2 * H_ * B_);
                const unsigned short* fp = ft + ((size_t)(t + 1) * G2_ + j) * B_ + b0;
                pfr = *(const ushortx4*)(fp);
                pfi = *(const ushortx4*)(fp + (size_t)H_ * B_);
            }
            const unsigned tgt = (unsigned)(t + 1);
            unsigned v;
            do {
                v = __hip_atomic_load(&myflags[lane & 31], __ATOMIC_RELAXED,
                                      __HIP_MEMORY_SCOPE_AGENT);
            } while (__any((int)(v < tgt)));
            // no acquire fence: hA reads are sc0/sc1 (LLC) and cannot see
            // stale L1/L2; producer vmcnt(0) ordered data before flag.
        } else {
            #pragma unroll
            for (int r = 0; r < 4; ++r) {
                out[(size_t)(b0 + r) * (S_ * H_) + (size_t)t * H_ + j] = hy[r];
                hfin[(size_t)(b0 + r) * H_ + j] = hy[r];
            }
        }
    }
}

extern "C" void kernel_launch(void* const* d_in, const int* in_sizes, int n_in,
                              void* d_out, int out_size, void* d_ws, size_t ws_size,
                              hipStream_t stream) {
    const float* input_feats = (const float*)d_in[0];  // [B,S,D]
    const float* aux_feats   = (const float*)d_in[1];  // [A,B,S,D]
    const float* hx          = (const float*)d_in[2];  // [B,H]
    const float* w_ih        = (const float*)d_in[3];  // [3H,D]
    const float* w_fh        = (const float*)d_in[4];  // [A,2H,D]
    const float* b_ih        = (const float*)d_in[5];  // [3H]
    const float* b_fh        = (const float*)d_in[6];  // [A,2H]
    const float* w_hh        = (const float*)d_in[7];  // [3H,H]
    const float* b_hh        = (const float*)d_in[8];  // [3H]
    float* out = (float*)d_out;

    // workspace (~340 MB). X_bf/AUX_bf live inside the git/ft zone (dead by
    // the time the transposes write git/ft).
    char* ws = (char*)d_ws;
    size_t off = 0;
    unsigned short* git  = (unsigned short*)(ws + off); off += (size_t)S_ * G3_ * B_ * 2; // 100.7 MB
    unsigned short* ft   = (unsigned short*)(ws + off); off += (size_t)S_ * G2_ * B_ * 2; //  67.1 MB
    unsigned short* gi_b = (unsigned short*)(ws + off); off += (size_t)M_ * G3_ * 2;      // 100.7 MB
    unsigned short* f_b  = (unsigned short*)(ws + off); off += (size_t)M_ * G2_ * 2;      //  67.1 MB
    unsigned short* Wih_bf = (unsigned short*)(ws + off); off += (size_t)G3_ * D_ * 2;    //   1.6 MB
    unsigned short* Wfh_bf = (unsigned short*)(ws + off); off += (size_t)2 * G2_ * D_ * 2;//   2.1 MB
    unsigned short* hA   = (unsigned short*)(ws + off); off += (size_t)2 * 32768 * 2;     // 128 KB
    unsigned*       flags = (unsigned*)(ws + off);      off += 512;
    unsigned short* X_bf   = git;                        // 33.6 MB, inside git zone
    unsigned short* AUX_bf = git + (size_t)M_ * D_;      // 67.1 MB, inside git zone

    dim3 blk(256);

    // bf16 pre-converts
    cvt_bf16<<<dim3((M_ * D_) / 1024), blk, 0, stream>>>(input_feats, X_bf, M_ * D_);
    cvt_bf16<<<dim3((2 * M_ * D_) / 1024), blk, 0, stream>>>(aux_feats, AUX_bf, 2 * M_ * D_);
    cvt_bf16<<<dim3((G3_ * D_) / 1024), blk, 0, stream>>>(w_ih, Wih_bf, G3_ * D_);
    cvt_bf16<<<dim3((2 * G2_ * D_) / 1024), blk, 0, stream>>>(w_fh, Wfh_bf, 2 * G2_ * D_);

    // projections (128x128 tiles)
    proj_gemm128<<<dim3(M_ / 128, G3_ / 128), blk, 0, stream>>>(
        X_bf, Wih_bf, b_ih, gi_b, G3_, 1, 1.0f, 0, 0);
    proj_gemm128<<<dim3(M_ / 128, G2_ / 128), blk, 0, stream>>>(
        AUX_bf, Wfh_bf, b_fh, f_b, G2_, 2, 0.5f,
        (size_t)M_ * D_, (size_t)G2_ * D_);

    // transpose to [S][G][B] (clobbers X_bf/AUX_bf — dead)
    transpose_to_sgb<<<dim3(S_, G3_ / 64), blk, 0, stream>>>(gi_b, git, G3_);
    transpose_to_sgb<<<dim3(S_, G2_ / 64), blk, 0, stream>>>(f_b, ft, G2_);

    scan_init<<<dim3(M_ / 256), blk, 0, stream>>>(hx, hA, flags);   // full 32768 coverage

    scan_persist<<<dim3(128), dim3(64), 0, stream>>>(
        git, ft, w_hh, b_hh, hx, hA, flags, out, out + (size_t)B_ * S_ * H_);
}

// Round 5
// 2275.983 us; speedup vs baseline: 1.0031x; 1.0031x over previous
//
#include <hip/hip_runtime.h>
#include <hip/hip_bf16.h>
#include <cstdint>

// Problem constants: H=512, B=64, S=512, D=512, N_AUX=2
#define B_ 64
#define S_ 512
#define D_ 512
#define H_ 512
#define M_ (B_*S_)   // 32768
#define G3_ (3*H_)   // 1536
#define G2_ (2*H_)   // 1024

using floatx4  = __attribute__((ext_vector_type(4))) float;
using shortx8  = __attribute__((ext_vector_type(8))) short;
using ushortx4 = __attribute__((ext_vector_type(4))) unsigned short;
using uintx4   = __attribute__((ext_vector_type(4))) unsigned int;

__device__ __forceinline__ unsigned short f32_to_bf16(float f) {
    union { float f; uint32_t u; } v; v.f = f;
    uint32_t u = v.u;
    return (unsigned short)((u + 0x7FFFu + ((u >> 16) & 1u)) >> 16);
}
__device__ __forceinline__ float bf16_to_f32(unsigned short s) {
    union { uint32_t u; float f; } v; v.u = ((uint32_t)s) << 16;
    return v.f;
}

// LLC-coherent (device coherent point) access helpers. sc0 sc1 bypass the
// per-CU L1 and the per-XCD L2, completing at the MALL/LLC — correct for
// cross-XCD producer/consumer without any cache-wide wbinv ops.
__device__ __forceinline__ void store_llc_b64(void* p, unsigned long long v) {
    asm volatile("global_store_dwordx2 %0, %1, off sc0 sc1"
                 :: "v"(p), "v"(v) : "memory");
}
__device__ __forceinline__ uintx4 load_llc_b128(const void* p) {
    uintx4 r;
    asm volatile("global_load_dwordx4 %0, %1, off sc0 sc1"
                 : "=v"(r) : "v"(p) : "memory");
    return r;
}

// ---------------------------------------------------------------------------
// fp32 -> bf16 bulk convert (n % 4 == 0)
// ---------------------------------------------------------------------------
__global__ __launch_bounds__(256) void cvt_bf16(
    const float* __restrict__ in, unsigned short* __restrict__ outp, int n)
{
    int idx = (blockIdx.x * 256 + threadIdx.x) * 4;
    if (idx < n) {
        floatx4 v = *(const floatx4*)(in + idx);
        ushortx4 o;
        #pragma unroll
        for (int u = 0; u < 4; ++u) o[u] = f32_to_bf16(v[u]);
        *(ushortx4*)(outp + idx) = o;
    }
}

// ---------------------------------------------------------------------------
// 128x128-tile bf16 MFMA GEMM (m93-style, register-staged LDS, padded rows).
// out[(s*B+b)][n] = scale * ( sum_a A_a[m,:].W_a[n,:] + sum_a bias_a[n] ),
// m = b*S + s. A bf16 [streams][M][512], W bf16 [streams][N][512].
// ---------------------------------------------------------------------------
#define LDK 40   // 32 + 8 shorts pad: row stride 80B = 20 banks -> conflict-free
__global__ __launch_bounds__(256) void proj_gemm128(
    const unsigned short* __restrict__ A, const unsigned short* __restrict__ Wb,
    const float* __restrict__ bias, unsigned short* __restrict__ out,
    int N, int nstreams, float scale, size_t a_stride, size_t w_stride)
{
    __shared__ unsigned short ldsA[128 * LDK];
    __shared__ unsigned short ldsB[128 * LDK];
    const int tid  = threadIdx.x;
    const int lane = tid & 63;
    const int wv   = tid >> 6;
    const int m0   = blockIdx.x * 128;
    const int n0   = blockIdx.y * 128;
    const int wm   = (wv & 1) * 64;
    const int wn   = (wv >> 1) * 64;
    const int srow  = tid >> 2;   // 0..63
    const int spart = tid & 3;    // 0..3

    floatx4 acc[4][4] = {};

    for (int a = 0; a < nstreams; ++a) {
        const unsigned short* Aa = A  + (size_t)a * a_stride;
        const unsigned short* Wa = Wb + (size_t)a * w_stride;
        for (int kt = 0; kt < 16; ++kt) {
            const int k0 = kt * 32;
            #pragma unroll
            for (int h = 0; h < 2; ++h) {
                int row = srow + h * 64;
                *(shortx8*)(ldsA + row * LDK + spart * 8) =
                    *(const shortx8*)(Aa + (size_t)(m0 + row) * 512 + k0 + spart * 8);
                *(shortx8*)(ldsB + row * LDK + spart * 8) =
                    *(const shortx8*)(Wa + (size_t)(n0 + row) * 512 + k0 + spart * 8);
            }
            __syncthreads();
            shortx8 af[4], bf[4];
            #pragma unroll
            for (int i = 0; i < 4; ++i)
                af[i] = *(const shortx8*)(ldsA + (wm + i * 16 + (lane & 15)) * LDK + (lane >> 4) * 8);
            #pragma unroll
            for (int j = 0; j < 4; ++j)
                bf[j] = *(const shortx8*)(ldsB + (wn + j * 16 + (lane & 15)) * LDK + (lane >> 4) * 8);
            #pragma unroll
            for (int i = 0; i < 4; ++i)
                #pragma unroll
                for (int j = 0; j < 4; ++j)
                    acc[i][j] = __builtin_amdgcn_mfma_f32_16x16x32_bf16(af[i], bf[j], acc[i][j], 0, 0, 0);
            __syncthreads();
        }
    }

    #pragma unroll
    for (int j = 0; j < 4; ++j) {
        int n = n0 + wn + j * 16 + (lane & 15);
        float bsum = 0.f;
        for (int a = 0; a < nstreams; ++a) bsum += bias[a * N + n];
        #pragma unroll
        for (int i = 0; i < 4; ++i) {
            #pragma unroll
            for (int r = 0; r < 4; ++r) {
                int m = m0 + wm + i * 16 + (lane >> 4) * 4 + r;
                int b = m >> 9, s = m & (S_ - 1);
                out[((size_t)s * B_ + b) * N + n] = f32_to_bf16(scale * (acc[i][j][r] + bsum));
            }
        }
    }
}

// ---------------------------------------------------------------------------
// Transpose bf16 [S][B][G] -> [S][G][B] — vectorized (ushortx4 both phases).
// Load: 16 lanes x 8B = 128B contiguous per quarter-wave (b-row, g-run).
// Store: 16 lanes x 8B = 128B contiguous per g-row (b-run).
// LDS tile padded to 68 (136B row stride, 8B-aligned for ushortx4; read
// phase worst case 4-way bank conflict on cheap scalar reads).
// ---------------------------------------------------------------------------
__global__ __launch_bounds__(256) void transpose_to_sgb(
    const unsigned short* __restrict__ in, unsigned short* __restrict__ out, int G)
{
    __shared__ unsigned short tile[64][68];
    const int s  = blockIdx.x;
    const int g0 = blockIdx.y * 64;
    const int bl = threadIdx.x >> 4;          // 0..15
    const int gl = (threadIdx.x & 15) * 4;    // 0,4,...,60
    #pragma unroll
    for (int it = 0; it < 4; ++it) {
        int b = it * 16 + bl;
        ushortx4 v = *(const ushortx4*)(in + ((size_t)s * B_ + b) * G + g0 + gl);
        *(ushortx4*)(&tile[b][gl]) = v;       // row stride 136B: gl*2 % 8 == 0 -> aligned
    }
    __syncthreads();
    const int gr = threadIdx.x >> 4;          // 0..15
    const int br = (threadIdx.x & 15) * 4;    // 0,4,...,60
    #pragma unroll
    for (int it = 0; it < 4; ++it) {
        int g = it * 16 + gr;
        ushortx4 v;
        v[0] = tile[br + 0][g];
        v[1] = tile[br + 1][g];
        v[2] = tile[br + 2][g];
        v[3] = tile[br + 3][g];
        *(ushortx4*)(out + ((size_t)s * G + g0 + g) * B_ + br) = v;
    }
}

// ---------------------------------------------------------------------------
// Scan init: hA[0] from hx in A-fragment layout; zero flags.
// hA short index for (b,j): ((j>>5)*4+(b>>4))*512 + ((j>>3)&3)*128 + (b&15)*8 + (j&7)
// ---------------------------------------------------------------------------
__global__ __launch_bounds__(256) void scan_init(
    const float* __restrict__ hx, unsigned short* __restrict__ hA,
    unsigned* __restrict__ flags)
{
    int idx = blockIdx.x * 256 + threadIdx.x;   // 0..32767 (grid 128!)
    int b = idx >> 9, j = idx & (H_ - 1);
    hA[(size_t)((j >> 5) * 4 + (b >> 4)) * 512 + ((j >> 3) & 3) * 128 + (b & 15) * 8 + (j & 7)]
        = f32_to_bf16(hx[idx]);
    if (idx < 128) flags[idx] = 0;
}

// ---------------------------------------------------------------------------
// Persistent scan (R1-proven flag protocol, reverted verbatim).
// 128 blocks x 64 threads (1 wave). Block = (bg = blk>>5, jsl = blk&31):
// owns j = jsl*16..+16, b-group bg (16 b). W frags in LDS.
//
// Fence-free handoff: hA + flags accessed ONLY via sc0/sc1 (LLC-coherent)
// ops. Producer: hA store -> s_waitcnt vmcnt(0) -> relaxed agent flag store.
// Consumer: relaxed agent flag poll -> batched sc0/sc1 hA loads.
// ---------------------------------------------------------------------------
__global__ __launch_bounds__(64) void scan_persist(
    const unsigned short* __restrict__ git,  // [S][3H][B] bf16
    const unsigned short* __restrict__ ft,   // [S][2H][B] bf16
    const float* __restrict__ Whh,           // [3H][H]
    const float* __restrict__ bhh,           // [3H]
    const float* __restrict__ hx,            // [B][H]
    unsigned short* __restrict__ hA,         // [2][32768] bf16
    unsigned* __restrict__ flags,            // [128]
    float* __restrict__ out,                 // [B][S][H]
    float* __restrict__ hfin)                // [B][H]
{
    __shared__ shortx8 ldsW[3 * 16 * 64];    // 48 KB
    __shared__ unsigned short repack[256];   // 512 B

    const int lane = threadIdx.x;
    const int jsl  = blockIdx.x & 31;
    const int bg   = blockIdx.x >> 5;
    const int j0   = jsl * 16;
    const int jn   = lane & 15;
    const int q    = lane >> 4;
    const int j    = j0 + jn;
    const int b0   = bg * 16 + q * 4;

    // one-time: W fragments -> LDS
    #pragma unroll
    for (int g = 0; g < 3; ++g) {
        const float* wrow = Whh + (size_t)(g * H_ + j0 + jn) * H_ + q * 8;
        for (int kt = 0; kt < 16; ++kt) {
            floatx4 w0 = *(const floatx4*)(wrow + kt * 32);
            floatx4 w1 = *(const floatx4*)(wrow + kt * 32 + 4);
            shortx8 wf;
            #pragma unroll
            for (int u = 0; u < 4; ++u) {
                wf[u]     = (short)f32_to_bf16(w0[u]);
                wf[u + 4] = (short)f32_to_bf16(w1[u]);
            }
            ldsW[(g * 16 + kt) * 64 + lane] = wf;
        }
    }
    const float brg = bhh[j], big = bhh[H_ + j], bng = bhh[2 * H_ + j];

    float hprev[4];
    #pragma unroll
    for (int r = 0; r < 4; ++r) hprev[r] = hx[(size_t)(b0 + r) * H_ + j];

    // gate prefetch registers (t = 0)
    ushortx4 pgr, pgi, pgn, pfr, pfi;
    {
        const unsigned short* gp = git + ((size_t)j) * B_ + b0;
        pgr = *(const ushortx4*)(gp);
        pgi = *(const ushortx4*)(gp + (size_t)H_ * B_);
        pgn = *(const ushortx4*)(gp + (size_t)2 * H_ * B_);
        const unsigned short* fp = ft + ((size_t)j) * B_ + b0;
        pfr = *(const ushortx4*)(fp);
        pfi = *(const ushortx4*)(fp + (size_t)H_ * B_);
    }

    const int slab = (jsl >> 1) * 4 + bg;
    unsigned* myflags = flags + bg * 32;

    for (int t = 0; t < S_; ++t) {
        const int buf = t & 1, nbuf = buf ^ 1;

        // --- batched hA fragment loads (pay LLC latency once) -------------
        const unsigned short* hAp = hA + (size_t)buf * 32768 + (size_t)(bg * 64 + lane) * 8;
        uintx4 af16[16];
        #pragma unroll
        for (int kt = 0; kt < 16; ++kt)
            af16[kt] = load_llc_b128(hAp + (size_t)kt * 2048);
        asm volatile("s_waitcnt vmcnt(0)" ::: "memory");
        __builtin_amdgcn_sched_barrier(0);   // keep MFMAs below the waitcnt

        floatx4 ar = {0.f,0.f,0.f,0.f}, ai = {0.f,0.f,0.f,0.f}, an = {0.f,0.f,0.f,0.f};
        #pragma unroll
        for (int kt = 0; kt < 16; ++kt) {
            shortx8 af = __builtin_bit_cast(shortx8, af16[kt]);
            ar = __builtin_amdgcn_mfma_f32_16x16x32_bf16(af, ldsW[(0 * 16 + kt) * 64 + lane], ar, 0, 0, 0);
            ai = __builtin_amdgcn_mfma_f32_16x16x32_bf16(af, ldsW[(1 * 16 + kt) * 64 + lane], ai, 0, 0, 0);
            an = __builtin_amdgcn_mfma_f32_16x16x32_bf16(af, ldsW[(2 * 16 + kt) * 64 + lane], an, 0, 0, 0);
        }

        float hy[4];
        #pragma unroll
        for (int r = 0; r < 4; ++r) {
            const float cr = bf16_to_f32(pgr[r]) + bf16_to_f32(pfr[r]);
            const float ci = bf16_to_f32(pgi[r]) + bf16_to_f32(pfi[r]);
            const float cn = bf16_to_f32(pgn[r]);
            const float rg = 1.f / (1.f + __expf(-(cr + ar[r] + brg)));
            const float ig = 1.f / (1.f + __expf(-(ci + ai[r] + big)));
            const float ng = tanhf(cn + rg * (an[r] + bng));
            hy[r] = ng + ig * (hprev[r] - ng);
            hprev[r] = hy[r];
            repack[(jn >> 3) * 128 + (q * 4 + r) * 8 + (jn & 7)] = f32_to_bf16(hy[r]);
        }
        __syncthreads();   // LDS repack visibility within the wave

        {   // publish h slab to LLC (bypass L1/L2)
            unsigned long long v = *(const unsigned long long*)(repack + lane * 4);
            store_llc_b64(hA + (size_t)nbuf * 32768 + (size_t)slab * 512
                          + (jsl & 1) * 256 + lane * 4, v);
        }

        if (t < S_ - 1) {
            // data-before-flag ordering: wait for hA store completion at LLC
            asm volatile("s_waitcnt vmcnt(0)" ::: "memory");
            if (lane == 0)
                __hip_atomic_store(&myflags[jsl], (unsigned)(t + 1),
                                   __ATOMIC_RELAXED, __HIP_MEMORY_SCOPE_AGENT);
            // off-critical-path work drains during the spin:
            #pragma unroll
            for (int r = 0; r < 4; ++r)
                out[(size_t)(b0 + r) * (S_ * H_) + (size_t)t * H_ + j] = hy[r];
            {   // prefetch gates for t+1 (plain cached loads — L2 stays warm)
                const unsigned short* gp = git + ((size_t)(t + 1) * G3_ + j) * B_ + b0;
                pgr = *(const ushortx4*)(gp);
                pgi = *(const ushortx4*)(gp + (size_t)H_ * B_);
                pgn = *(const ushortx4*)(gp + (size_t)2 * H_ * B_);
                const unsigned short* fp = ft + ((size_t)(t + 1) * G2_ + j) * B_ + b0;
                pfr = *(const ushortx4*)(fp);
                pfi = *(const ushortx4*)(fp + (size_t)H_ * B_);
            }
            const unsigned tgt = (unsigned)(t + 1);
            unsigned v;
            do {
                v = __hip_atomic_load(&myflags[lane & 31], __ATOMIC_RELAXED,
                                      __HIP_MEMORY_SCOPE_AGENT);
            } while (__any((int)(v < tgt)));
            // no acquire fence: hA reads are sc0/sc1 (LLC) and cannot see
            // stale L1/L2; producer vmcnt(0) ordered data before flag.
        } else {
            #pragma unroll
            for (int r = 0; r < 4; ++r) {
                out[(size_t)(b0 + r) * (S_ * H_) + (size_t)t * H_ + j] = hy[r];
                hfin[(size_t)(b0 + r) * H_ + j] = hy[r];
            }
        }
    }
}

extern "C" void kernel_launch(void* const* d_in, const int* in_sizes, int n_in,
                              void* d_out, int out_size, void* d_ws, size_t ws_size,
                              hipStream_t stream) {
    const float* input_feats = (const float*)d_in[0];  // [B,S,D]
    const float* aux_feats   = (const float*)d_in[1];  // [A,B,S,D]
    const float* hx          = (const float*)d_in[2];  // [B,H]
    const float* w_ih        = (const float*)d_in[3];  // [3H,D]
    const float* w_fh        = (const float*)d_in[4];  // [A,2H,D]
    const float* b_ih        = (const float*)d_in[5];  // [3H]
    const float* b_fh        = (const float*)d_in[6];  // [A,2H]
    const float* w_hh        = (const float*)d_in[7];  // [3H,H]
    const float* b_hh        = (const float*)d_in[8];  // [3H]
    float* out = (float*)d_out;

    // workspace (~340 MB). X_bf/AUX_bf live inside the git/ft zone (dead by
    // the time the transposes write git/ft).
    char* ws = (char*)d_ws;
    size_t off = 0;
    unsigned short* git  = (unsigned short*)(ws + off); off += (size_t)S_ * G3_ * B_ * 2; // 100.7 MB
    unsigned short* ft   = (unsigned short*)(ws + off); off += (size_t)S_ * G2_ * B_ * 2; //  67.1 MB
    unsigned short* gi_b = (unsigned short*)(ws + off); off += (size_t)M_ * G3_ * 2;      // 100.7 MB
    unsigned short* f_b  = (unsigned short*)(ws + off); off += (size_t)M_ * G2_ * 2;      //  67.1 MB
    unsigned short* Wih_bf = (unsigned short*)(ws + off); off += (size_t)G3_ * D_ * 2;    //   1.6 MB
    unsigned short* Wfh_bf = (unsigned short*)(ws + off); off += (size_t)2 * G2_ * D_ * 2;//   2.1 MB
    unsigned short* hA   = (unsigned short*)(ws + off); off += (size_t)2 * 32768 * 2;     // 128 KB
    unsigned*       flags = (unsigned*)(ws + off);      off += 512;
    unsigned short* X_bf   = git;                        // 33.6 MB, inside git zone
    unsigned short* AUX_bf = git + (size_t)M_ * D_;      // 67.1 MB, inside git zone

    dim3 blk(256);

    // bf16 pre-converts
    cvt_bf16<<<dim3((M_ * D_) / 1024), blk, 0, stream>>>(input_feats, X_bf, M_ * D_);
    cvt_bf16<<<dim3((2 * M_ * D_) / 1024), blk, 0, stream>>>(aux_feats, AUX_bf, 2 * M_ * D_);
    cvt_bf16<<<dim3((G3_ * D_) / 1024), blk, 0, stream>>>(w_ih, Wih_bf, G3_ * D_);
    cvt_bf16<<<dim3((2 * G2_ * D_) / 1024), blk, 0, stream>>>(w_fh, Wfh_bf, 2 * G2_ * D_);

    // projections (128x128 tiles)
    proj_gemm128<<<dim3(M_ / 128, G3_ / 128), blk, 0, stream>>>(
        X_bf, Wih_bf, b_ih, gi_b, G3_, 1, 1.0f, 0, 0);
    proj_gemm128<<<dim3(M_ / 128, G2_ / 128), blk, 0, stream>>>(
        AUX_bf, Wfh_bf, b_fh, f_b, G2_, 2, 0.5f,
        (size_t)M_ * D_, (size_t)G2_ * D_);

    // transpose to [S][G][B] (clobbers X_bf/AUX_bf — dead)
    transpose_to_sgb<<<dim3(S_, G3_ / 64), blk, 0, stream>>>(gi_b, git, G3_);
    transpose_to_sgb<<<dim3(S_, G2_ / 64), blk, 0, stream>>>(f_b, ft, G2_);

    scan_init<<<dim3(M_ / 256), blk, 0, stream>>>(hx, hA, flags);   // full 32768 coverage

    scan_persist<<<dim3(128), dim3(64), 0, stream>>>(
        git, ft, w_hh, b_hh, hx, hA, flags, out, out + (size_t)B_ * S_ * H_);
}